// Round 23
// baseline (31.745 us; speedup 1.0000x reference)
//
#include <hip/hip_runtime.h>

// AnatomicalConsistencyLoss: fused separable-Sobel magnitude + cosine loss.
// pred/target (2,1,160,160,160) f32 -> scalar f32.
// R23: ZERO-BARRIER main loop via wave-private staging. R22 proved the
// barrier quantum is the binding overhead (18->9 barriers = -1.4us). Here:
// each wave stages its OWN 6-row window (4 output rows + 2 halo; 240 dwords
// = exactly one GLD16/vol) into wave-private LDS double buffers. The row
// sharing that required s_barrier is replaced by ~33% redundant staging
// (cache-served). Main loop: s_waitcnt vmcnt(0) on the wave's own 2 loads
// (+sched_barrier, rule-18), issue next plane (full compute phase of cover,
// R18/R19-proven sufficient), consume. Four waves slip freely. Chunk-granular
// source clamp = R18's proven scheme (40-dword rows = 10 exact 4-dword
// chunks); fixLo/fixHi/yok selects zero halo garbage. Geometry/math
// unchanged: DC=16, 1000 blocks, XCD swizzle, pending-sum z-stream,
// packed-v2, fused transcendentals, two-kernel finalize.

constexpr int Dd = 160, Hh = 160, Ww = 160;
constexpr int TW = 32, TH = 16, DC = 16;
constexpr int NTX = Ww / TW;                 // 5
constexpr int NTY = Hh / TH;                 // 10
constexpr int NTZ = Dd / DC;                 // 10
constexpr int NBLOCKS = NTX * NTY * NTZ * 2; // 1000
constexpr int NXCD = 8;
constexpr int CHUNK = NBLOCKS / NXCD;        // 125
constexpr int PLANES = DC + 2;               // 18
constexpr int PLSZ = Hh * Ww;                // 25600
constexpr double NVOX = 2.0 * Dd * Hh * Ww;  // 8,192,000

constexpr int SPANF = 40;                    // floats staged per row
constexpr int WROWS = 6;                     // rows per wave window (4 out + 2 halo)
constexpr int WVOLD = WROWS * SPANF;         // 240 dwords of real data
constexpr int WVOLF = 256;                   // padded: 64 lanes x 4 dwords

typedef float v2 __attribute__((ext_vector_type(2)));
typedef float v4 __attribute__((ext_vector_type(4)));

#define GLD16(g, l)                                                     \
    __builtin_amdgcn_global_load_lds(                                   \
        (const __attribute__((address_space(1))) void*)(g),             \
        (__attribute__((address_space(3))) void*)(l), 16, 0, 0)

__global__ __launch_bounds__(256)
void acl_partial(const float* __restrict__ pred, const float* __restrict__ targ,
                 float2* __restrict__ partial)
{
    __shared__ float sv[4][2][2][WVOLF];   // [wave][buf][vol][256], 16 KB
    __shared__ float rred[8];

    const int tid  = threadIdx.x;
    const int lane = tid & 63;
    const int w    = tid >> 6;        // wave 0..3
    const int gx   = lane & 15;       // x-group of 2 output cols
    const int lw   = lane >> 4;       // local row 0..3; global row r = 4w+lw (+y0)

    // ---- XCD-chunked bijective swizzle + decode (zt fastest, wt, ht, b) ----
    const int bid = blockIdx.x;
    const int swz = (bid % NXCD) * CHUNK + bid / NXCD;
    const int zt  = swz % NTZ;
    const int t1  = swz / NTZ;
    const int wt  = t1 % NTX;
    const int t2  = t1 / NTX;
    const int ht  = t2 % NTY;
    const int b   = t2 / NTY;

    const int x0 = wt * TW, y0 = ht * TH;
    const int z0 = zt * DC;
    const size_t base = (size_t)b * ((size_t)Dd * PLSZ);
    const float* __restrict__ pv = pred + base;
    const float* __restrict__ tv = targ + base;

    // ---- staging constants (per-lane, loop-invariant) ----
    // wave window covers global rows wr0..wr0+5, cols x0-4..x0+35
    const int wr0 = y0 + 4 * w - 1;
    int d = lane * 4;  if (d > WVOLD - 4) d = WVOLD - 4;   // pad lanes: dup chunk
    const int srow = d / SPANF;
    const int scol = d - srow * SPANF;                     // multiple of 4
    int sgy = wr0 + srow;  sgy = sgy < 0 ? 0 : (sgy > Hh - 1 ? Hh - 1 : sgy);
    int sgx = x0 - 4 + scol; sgx = sgx < 0 ? 0 : (sgx > Ww - 4 ? Ww - 4 : sgx);
    const int splaneoff = sgy * Ww + sgx;

    // ---- consume constants ----
    const bool blkLo = (x0 == 0);
    const bool blkHi = (x0 + TW == Ww);
    const bool fixLo = blkLo && (gx == 0);
    const bool fixHi = blkHi && (gx == 15);
    const int  gr    = y0 + 4 * w + lw;          // this thread's output row
    const bool yokm  = (gr - 1 >= 0);
    const bool yokp  = (gr + 1 < Hh);
    const int  rb    = lw * SPANF + 2 * gx + 3;  // window row lw = global row gr-1

    const v2 z2 = {0.f, 0.f};
    const v4 z4 = {0.f, 0.f, 0.f, 0.f};

    // streaming pending partial gradients (named v2 scalars only)
    v2 P1x = z2, P1y = z2, P1z = z2, P2x = z2, P2y = z2, P2z = z2;
    v2 T1x = z2, T1y = z2, T1z = z2, T2x = z2, T2y = z2, T2z = z2;
    v2 accm = z2, accc = z2;

    auto stage = [&](int p1, int buf) {   // wave-private: 2 GLD16 per wave
        int gz = z0 - 1 + p1;
        gz = gz < 0 ? 0 : (gz > Dd - 1 ? Dd - 1 : gz);
        GLD16(pv + (ptrdiff_t)gz * PLSZ + splaneoff, &sv[w][buf][0][0]);
        GLD16(tv + (ptrdiff_t)gz * PLSZ + splaneoff, &sv[w][buf][1][0]);
    };

    // read 4-float span [X-1..X+2] of one window row; zero invalid floats
    auto loadRow = [&](const float* S, int idx, bool valid) -> v4 {
        v4 row;
        row.x = fixLo ? 0.f : S[idx];
        row.y = S[idx + 1];
        row.z = S[idx + 2];
        row.w = fixHi ? 0.f : S[idx + 3];
        if (!valid) row = z4;
        return row;
    };

    auto consumeVol = [&](const float* S, v2& A, v2& B, v2& C) {
        const v4 m = loadRow(S, rb,             yokm);
        const v4 c = loadRow(S, rb + SPANF,     true);
        const v4 p = loadRow(S, rb + 2 * SPANF, yokp);
        const v2 HSm = m.xy + 2.f*m.yz + m.zw;
        const v2 HDm = m.zw - m.xy;
        const v2 HS0 = c.xy + 2.f*c.yz + c.zw;
        const v2 HD0 = c.zw - c.xy;
        const v2 HSp = p.xy + 2.f*p.yz + p.zw;
        const v2 HDp = p.zw - p.xy;
        A = HSm + 2.f*HS0 + HSp;   // sm_y(sm_x) -> z-deriv path
        B = HDm + 2.f*HD0 + HDp;   // sm_y(d_x)  -> x-gradient
        C = HSp - HSm;             // d_y(sm_x)  -> y-gradient
    };

    stage(0, 0);

    #pragma unroll 1
    for (int p = 0; p < PLANES; ++p) {
        const int buf = p & 1;

        // wait the wave's OWN staged loads for plane p (no cross-wave sync)
        asm volatile("s_waitcnt vmcnt(0)" ::: "memory");
        __builtin_amdgcn_sched_barrier(0);

        // issue plane p+1 into the other buffer (its iter-(p-1) reads are
        // long consumed); gets the full compute phase below as latency cover
        if (p + 1 < PLANES) stage(p + 1, buf ^ 1);

        const bool zok = ((unsigned)(z0 - 1 + p) < (unsigned)Dd);   // wave-uniform

        v2 A, B, C;
        consumeVol(&sv[w][buf][0][0], A, B, C);
        if (!zok) { A = z2; B = z2; C = z2; }
        const v2 fpx = P1x + B, fpy = P1y + C, fpz = A - P1z;
        P1x = 2.f*B + P2x;  P1y = 2.f*C + P2y;  P1z = P2z;
        P2x = B;  P2y = C;  P2z = A;

        consumeVol(&sv[w][buf][1][0], A, B, C);
        if (!zok) { A = z2; B = z2; C = z2; }
        const v2 ftx = T1x + B, fty = T1y + C, ftz = A - T1z;
        T1x = 2.f*B + T2x;  T1y = 2.f*C + T2y;  T1z = T2z;
        T2x = B;  T2y = C;  T2z = A;

        if (p >= 2) {   // output plane z0 + (p-2) finalized
            // fused: (pm-tm)^2 = a+b-2*sqrt(ab);  rsq(np2)*rsq(nt2)=rsq(np2*nt2)
            const v2 np2 = fpx*fpx + fpy*fpy + fpz*fpz;
            const v2 nt2 = ftx*ftx + fty*fty + ftz*ftz;
            const v2 a  = np2 + 1e-8f;
            const v2 bb = nt2 + 1e-8f;
            const v2 ab = a * bb;
            v2 rt;
            rt.x = __builtin_amdgcn_sqrtf(ab.x);
            rt.y = __builtin_amdgcn_sqrtf(ab.y);
            accm += a + bb - 2.f*rt;
            const v2 dt = fpx*ftx + fpy*fty + fpz*ftz;
            v2 pr = np2 * nt2;
            pr.x = fmaxf(pr.x, 1e-30f);
            pr.y = fmaxf(pr.y, 1e-30f);
            v2 rq;
            rq.x = __builtin_amdgcn_rsqf(pr.x);
            rq.y = __builtin_amdgcn_rsqf(pr.y);
            accc += dt * rq;
        }
        // no barrier: LDS is wave-private; WAR on buf^1 is ordered by this
        // wave's own program order (reads of it finished last iteration).
    }

    // ---- block reduction (only cross-wave sync in the kernel) ----
    float am = accm.x + accm.y;
    float ac = accc.x + accc.y;
    #pragma unroll
    for (int off = 32; off >= 1; off >>= 1) {
        am += __shfl_down(am, off);
        ac += __shfl_down(ac, off);
    }
    if ((tid & 63) == 0) { rred[w] = am; rred[4 + w] = ac; }
    __syncthreads();
    if (tid == 0) {
        const float m = rred[0] + rred[1] + rred[2] + rred[3];
        const float c = rred[4] + rred[5] + rred[6] + rred[7];
        partial[bid] = make_float2(m, c);
    }
}

__global__ __launch_bounds__(256)
void acl_final(const float2* __restrict__ partial, float* __restrict__ out)
{
    __shared__ double sm[256], sc[256];
    double m = 0.0, c = 0.0;
    for (int i = threadIdx.x; i < NBLOCKS; i += 256) {
        const float2 v = partial[i];
        m += (double)v.x;
        c += (double)v.y;
    }
    sm[threadIdx.x] = m;
    sc[threadIdx.x] = c;
    __syncthreads();
    #pragma unroll
    for (int s = 128; s >= 1; s >>= 1) {
        if (threadIdx.x < (unsigned)s) {
            sm[threadIdx.x] += sm[threadIdx.x + s];
            sc[threadIdx.x] += sc[threadIdx.x + s];
        }
        __syncthreads();
    }
    if (threadIdx.x == 0) {
        const double mag_loss = sm[0] / NVOX;
        const double dir_loss = 1.0 - sc[0] / NVOX;
        out[0] = (float)(0.2 * (mag_loss + dir_loss));
    }
}

extern "C" void kernel_launch(void* const* d_in, const int* in_sizes, int n_in,
                              void* d_out, int out_size, void* d_ws, size_t ws_size,
                              hipStream_t stream) {
    const float* pred = (const float*)d_in[0];
    const float* targ = (const float*)d_in[1];
    float* out = (float*)d_out;
    float2* partial = (float2*)d_ws;  // 1000 * 8 B = 8 KB

    acl_partial<<<NBLOCKS, 256, 0, stream>>>(pred, targ, partial);
    acl_final<<<1, 256, 0, stream>>>(partial, out);
}

// Round 24
// 31.058 us; speedup vs baseline: 1.0221x; 1.0221x over previous
//
#include <hip/hip_runtime.h>

// AnatomicalConsistencyLoss: fused separable-Sobel magnitude + cosine loss.
// pred/target (2,1,160,160,160) f32 -> scalar f32.
// R24 = R22 (best 31.19us) with THREE planes per barrier interval.
// Lever history: 1 plane/barrier = 32.55 (R18), 2 = 31.19 (R22), wave-private
// 0-barrier = neutral (R23), conflict-fix = neutral (R21, LDS pipe hidden).
// The kernel is dependency-bound with all pipes at 40-50%; widening the
// barrier quantum adds per-wave ILP (3 planes' chains interleave) and
// amortizes barrier straggle: barriers 18 -> 6 (18 = 6x3 exact, no tail).
// 6 LDS plane-slots (36KB -> 4 blocks/CU >= 3.9 avg residency). Prologue
// stages planes 0-2; each interval stages the next triple (6 GLD16/wave,
// wid<3) then computes its triple before ONE __syncthreads (drains vmcnt ->
// staged data landed; orders slot reuse). Body/math/swizzle/finalize
// byte-identical to R22. Loop unroll PINNED (R16). Slot indices only touch
// LDS addressing (rule-20 safe).

constexpr int Dd = 160, Hh = 160, Ww = 160;
constexpr int TW = 32, TH = 16, DC = 16;
constexpr int NTX = Ww / TW;                 // 5
constexpr int NTY = Hh / TH;                 // 10
constexpr int NTZ = Dd / DC;                 // 10
constexpr int NBLOCKS = NTX * NTY * NTZ * 2; // 1000
constexpr int NXCD = 8;
constexpr int CHUNK = NBLOCKS / NXCD;        // 125
constexpr int PLANES = DC + 2;               // 18 = 6 intervals x 3 planes
constexpr int PLSZ = Hh * Ww;                // 25600
constexpr double NVOX = 2.0 * Dd * Hh * Ww;  // 8,192,000

constexpr int SPANF = 40;                    // floats staged per row (x0-4..x0+36)
constexpr int SROWS = TH + 2;                // 18 rows staged per plane
constexpr int VOLF  = 768;                   // padded vol region: 3*1024B

typedef float v2 __attribute__((ext_vector_type(2)));
typedef float v4 __attribute__((ext_vector_type(4)));

#define GLD16(g, l)                                                     \
    __builtin_amdgcn_global_load_lds(                                   \
        (const __attribute__((address_space(1))) void*)(g),             \
        (__attribute__((address_space(3))) void*)(l), 16, 0, 0)

__global__ __launch_bounds__(256)
void acl_partial(const float* __restrict__ pred, const float* __restrict__ targ,
                 float2* __restrict__ partial)
{
    __shared__ float sv[6][2][VOLF];   // [plane-slot][vol][row*40+col], 36 KB
    __shared__ float rred[8];

    const int tid  = threadIdx.x;
    const int lane = tid & 63;
    const int wid  = tid >> 6;
    const int gx   = tid & 15;        // x-group of 2 output cols
    const int r    = tid >> 4;        // row 0..15

    // ---- XCD-chunked bijective swizzle + decode (zt fastest, wt, ht, b) ----
    const int bid = blockIdx.x;
    const int swz = (bid % NXCD) * CHUNK + bid / NXCD;
    const int zt  = swz % NTZ;
    const int t1  = swz / NTZ;
    const int wt  = t1 % NTX;
    const int t2  = t1 / NTX;
    const int ht  = t2 % NTY;
    const int b   = t2 / NTY;

    const int x0 = wt * TW, y0 = ht * TH;
    const int z0 = zt * DC;
    const size_t base = (size_t)b * ((size_t)Dd * PLSZ);
    const float* __restrict__ pv = pred + base;
    const float* __restrict__ tv = targ + base;

    // ---- staging constants (per-lane, loop-invariant) ----
    const int so   = (wid < 3 ? wid : 0) * 1024 + lane * 16;        // byte off in vol region
    int srow = so / 160;  if (srow > SROWS - 1) srow = SROWS - 1;   // row (160B rows)
    const int scol = (so % 160) >> 2;                               // float col, mult of 4
    int sgy = y0 - 1 + srow;  sgy = sgy < 0 ? 0 : (sgy > Hh - 1 ? Hh - 1 : sgy);
    int sgx = x0 - 4 + scol;  sgx = sgx < 0 ? 0 : (sgx > Ww - 4 ? Ww - 4 : sgx);
    const int splaneoff = sgy * Ww + sgx;
    const int ldsoff = wid * 256;                                   // floats

    // ---- consume constants ----
    const bool blkLo = (x0 == 0);
    const bool blkHi = (x0 + TW == Ww);
    const bool fixLo = blkLo && (gx == 0);
    const bool fixHi = blkHi && (gx == 15);
    const bool yokm  = (y0 + r - 1 >= 0);
    const bool yokp  = (y0 + r + 1 < Hh);
    const int  rb    = r * SPANF + 2 * gx + 3;   // col of X-1 in row r

    const v2 z2 = {0.f, 0.f};
    const v4 z4 = {0.f, 0.f, 0.f, 0.f};

    // streaming pending partial gradients (named v2 scalars only)
    v2 P1x = z2, P1y = z2, P1z = z2, P2x = z2, P2y = z2, P2z = z2;
    v2 T1x = z2, T1y = z2, T1z = z2, T2x = z2, T2y = z2, T2z = z2;
    v2 accm = z2, accc = z2;

    auto stage = [&](int p1, int slot) {   // stage plane p1 (z = z0-1+p1)
        if (wid < 3) {
            int gz = z0 - 1 + p1;
            gz = gz < 0 ? 0 : (gz > Dd - 1 ? Dd - 1 : gz);
            const float* gp = pv + (ptrdiff_t)gz * PLSZ + splaneoff;
            const float* gt = tv + (ptrdiff_t)gz * PLSZ + splaneoff;
            GLD16(gp, &sv[slot][0][ldsoff]);
            GLD16(gt, &sv[slot][1][ldsoff]);
        }
    };

    // read 4-float span [X-1..X+2] of one staged row; zero invalid floats
    auto loadRow = [&](const float* S, int idx, bool valid) -> v4 {
        v4 row;
        row.x = fixLo ? 0.f : S[idx];
        row.y = S[idx + 1];
        row.z = S[idx + 2];
        row.w = fixHi ? 0.f : S[idx + 3];
        if (!valid) row = z4;
        return row;
    };

    auto consumeVol = [&](const float* S, v2& A, v2& B, v2& C) {
        const v4 m = loadRow(S, rb,             yokm);
        const v4 c = loadRow(S, rb + SPANF,     true);
        const v4 p = loadRow(S, rb + 2 * SPANF, yokp);
        const v2 HSm = m.xy + 2.f*m.yz + m.zw;
        const v2 HDm = m.zw - m.xy;
        const v2 HS0 = c.xy + 2.f*c.yz + c.zw;
        const v2 HD0 = c.zw - c.xy;
        const v2 HSp = p.xy + 2.f*p.yz + p.zw;
        const v2 HDp = p.zw - p.xy;
        A = HSm + 2.f*HS0 + HSp;   // sm_y(sm_x) -> z-deriv path
        B = HDm + 2.f*HD0 + HDp;   // sm_y(d_x)  -> x-gradient
        C = HSp - HSm;             // d_y(sm_x)  -> y-gradient
    };

    auto doPlane = [&](int p, int slot) {
        const bool zok = ((unsigned)(z0 - 1 + p) < (unsigned)Dd);   // wave-uniform

        v2 A, B, C;
        consumeVol(&sv[slot][0][0], A, B, C);
        if (!zok) { A = z2; B = z2; C = z2; }
        const v2 fpx = P1x + B, fpy = P1y + C, fpz = A - P1z;
        P1x = 2.f*B + P2x;  P1y = 2.f*C + P2y;  P1z = P2z;
        P2x = B;  P2y = C;  P2z = A;

        consumeVol(&sv[slot][1][0], A, B, C);
        if (!zok) { A = z2; B = z2; C = z2; }
        const v2 ftx = T1x + B, fty = T1y + C, ftz = A - T1z;
        T1x = 2.f*B + T2x;  T1y = 2.f*C + T2y;  T1z = T2z;
        T2x = B;  T2y = C;  T2z = A;

        if (p >= 2) {   // output plane z0 + (p-2) finalized
            // fused: (pm-tm)^2 = a+b-2*sqrt(ab);  rsq(np2)*rsq(nt2)=rsq(np2*nt2)
            const v2 np2 = fpx*fpx + fpy*fpy + fpz*fpz;
            const v2 nt2 = ftx*ftx + fty*fty + ftz*ftz;
            const v2 a  = np2 + 1e-8f;
            const v2 bb = nt2 + 1e-8f;
            const v2 ab = a * bb;
            v2 rt;
            rt.x = __builtin_amdgcn_sqrtf(ab.x);
            rt.y = __builtin_amdgcn_sqrtf(ab.y);
            accm += a + bb - 2.f*rt;
            const v2 dt = fpx*ftx + fpy*fty + fpz*ftz;
            v2 pr = np2 * nt2;
            pr.x = fmaxf(pr.x, 1e-30f);
            pr.y = fmaxf(pr.y, 1e-30f);
            v2 rq;
            rq.x = __builtin_amdgcn_rsqf(pr.x);
            rq.y = __builtin_amdgcn_rsqf(pr.y);
            accc += dt * rq;
        }
    };

    // ---- prologue: stage the first triple ----
    stage(0, 0);
    stage(1, 1);
    stage(2, 2);
    __syncthreads();

    #pragma unroll 1   // CRITICAL: rolled (6-trip loop is in unroll danger zone)
    for (int pp = 0; pp < PLANES; pp += 3) {
        const int s  = pp % 6;        // {0,3,0,3,...}: this triple's slots s,s+1,s+2
        const int s2 = s ^ 3;         // next triple's slots

        // stage the NEXT interval's three planes; fly under ~1050cy compute
        if (pp + 3 < PLANES) {
            stage(pp + 3, s2);
            stage(pp + 4, s2 + 1);
            stage(pp + 5, s2 + 2);
        }

        doPlane(pp,     s);
        doPlane(pp + 1, s + 1);
        doPlane(pp + 2, s + 2);

        // one barrier per THREE planes: (a) next triple's staged data landed
        // (syncthreads drains vmcnt), (b) slots s..s+2 fully read before the
        // next interval stages into them.
        __syncthreads();
    }

    // ---- block reduction ----
    float am = accm.x + accm.y;
    float ac = accc.x + accc.y;
    #pragma unroll
    for (int off = 32; off >= 1; off >>= 1) {
        am += __shfl_down(am, off);
        ac += __shfl_down(ac, off);
    }
    if ((tid & 63) == 0) { rred[wid] = am; rred[4 + wid] = ac; }
    __syncthreads();
    if (tid == 0) {
        const float m = rred[0] + rred[1] + rred[2] + rred[3];
        const float c = rred[4] + rred[5] + rred[6] + rred[7];
        partial[bid] = make_float2(m, c);
    }
}

__global__ __launch_bounds__(256)
void acl_final(const float2* __restrict__ partial, float* __restrict__ out)
{
    __shared__ double sm[256], sc[256];
    double m = 0.0, c = 0.0;
    for (int i = threadIdx.x; i < NBLOCKS; i += 256) {
        const float2 v = partial[i];
        m += (double)v.x;
        c += (double)v.y;
    }
    sm[threadIdx.x] = m;
    sc[threadIdx.x] = c;
    __syncthreads();
    #pragma unroll
    for (int s = 128; s >= 1; s >>= 1) {
        if (threadIdx.x < (unsigned)s) {
            sm[threadIdx.x] += sm[threadIdx.x + s];
            sc[threadIdx.x] += sc[threadIdx.x + s];
        }
        __syncthreads();
    }
    if (threadIdx.x == 0) {
        const double mag_loss = sm[0] / NVOX;
        const double dir_loss = 1.0 - sc[0] / NVOX;
        out[0] = (float)(0.2 * (mag_loss + dir_loss));
    }
}

extern "C" void kernel_launch(void* const* d_in, const int* in_sizes, int n_in,
                              void* d_out, int out_size, void* d_ws, size_t ws_size,
                              hipStream_t stream) {
    const float* pred = (const float*)d_in[0];
    const float* targ = (const float*)d_in[1];
    float* out = (float*)d_out;
    float2* partial = (float2*)d_ws;  // 1000 * 8 B = 8 KB

    acl_partial<<<NBLOCKS, 256, 0, stream>>>(pred, targ, partial);
    acl_final<<<1, 256, 0, stream>>>(partial, out);
}